// Round 8
// baseline (699.122 us; speedup 1.0000x reference)
//
#include <hip/hip_runtime.h>
#include <cstddef>
#include <cstdint>

#define B_  64
#define T_  51
#define H_  512
#define G4_ 2048
#define V_  32000
#define R_  (T_ * B_)   // 3264
#define NTILE 3250      // 26 m-tiles x 125 v-tiles
#define NFC   224       // FC consumer blocks (32..255)

typedef __attribute__((ext_vector_type(8))) short bf16x8;
typedef __attribute__((ext_vector_type(4))) float f32x4;
typedef __attribute__((ext_vector_type(4))) unsigned int u32x4;
typedef unsigned long long ull;

__device__ __forceinline__ uint16_t f2bf(float f) {   // RNE float->bf16
    uint32_t u = __float_as_uint(f);
    u += 0x7FFFu + ((u >> 16) & 1u);
    return (uint16_t)(u >> 16);
}
__device__ __forceinline__ float bf2f(uint32_t h) { return __uint_as_float(h << 16); }

// LLC-coherent ops (bypass L1+L2; correct across XCDs within a dispatch)
__device__ __forceinline__ void ldsc(u32x4& d, const uint32_t* p) {
    asm volatile("global_load_dwordx4 %0, %1, off sc0 sc1" : "=v"(d) : "v"(p));
}
__device__ __forceinline__ uint32_t ldflag(const uint32_t* p) {
    uint32_t v;
    asm volatile("global_load_dword %0, %1, off sc0 sc1\n\ts_waitcnt vmcnt(0)"
                 : "=v"(v) : "v"(p));
    return v;
}
__device__ __forceinline__ void stflag(uint32_t* p, uint32_t v) {
    asm volatile("global_store_dword %0, %1, off sc0 sc1" :: "v"(p), "v"(v) : "memory");
}
__device__ __forceinline__ void stsh(uint16_t* p, uint32_t v) {
    asm volatile("global_store_short %0, %1, off sc0 sc1" :: "v"(p), "v"(v) : "memory");
}

// ---------------------------------------------------------------- K0: init
__global__ __launch_bounds__(256) void k0_init(const float* __restrict__ x,
                                               uint16_t* __restrict__ hx,
                                               float* __restrict__ sumexp,
                                               uint32_t* __restrict__ flags) {
    int i = blockIdx.x * 256 + threadIdx.x;      // 0..32767
    if (i < B_ * H_) hx[i] = f2bf(x[i]);
    if (i < R_) sumexp[i] = 0.f;
    if (i < T_ * 128) flags[i] = 0;
}

// ---------------------------------------------------------------- Kcvt: f32 -> bf16
__global__ __launch_bounds__(256) void kcvt(const float* __restrict__ src,
                                            uint16_t* __restrict__ dst, int n8) {
    int i = blockIdx.x * 256 + threadIdx.x;
    if (i >= n8) return;
    const float4* s = (const float4*)src + (size_t)i * 2;
    float4 f0 = s[0], f1 = s[1];
    union { uint16_t h[8]; uint4 u; } p;
    p.h[0]=f2bf(f0.x); p.h[1]=f2bf(f0.y); p.h[2]=f2bf(f0.z); p.h[3]=f2bf(f0.w);
    p.h[4]=f2bf(f1.x); p.h[5]=f2bf(f1.y); p.h[6]=f2bf(f1.z); p.h[7]=f2bf(f1.w);
    ((uint4*)dst)[i] = p.u;
}

// ---------------------------------------------------------------- K1: Xg GEMM (bf16 MFMA)
// XgT[((t*512+u)*4+g)*64+b] = bf16( emb[tok(r)].W_ih[g*512+u] + b_ih + b_hh )
template<int CVT>
__global__ __launch_bounds__(256, 2) void k1_mfma(const int* __restrict__ labels,
                                                  const float* __restrict__ emb,
                                                  const void* __restrict__ wih,
                                                  const float* __restrict__ b_ih,
                                                  const float* __restrict__ b_hh,
                                                  uint16_t* __restrict__ XgT) {
    __shared__ uint16_t Al[64 * 72];
    __shared__ uint16_t Bl[256 * 72];
    const int t    = blockIdx.y;
    const int n0   = blockIdx.x * 256;
    const int tid  = threadIdx.x;
    const int w    = tid >> 6;
    const int lane = tid & 63;
    const int l15  = lane & 15;
    const int lhi  = lane >> 4;

    f32x4 acc[4][4];
    #pragma unroll
    for (int mi = 0; mi < 4; ++mi)
        #pragma unroll
        for (int nf = 0; nf < 4; ++nf) acc[mi][nf] = (f32x4){0.f, 0.f, 0.f, 0.f};

    for (int k0 = 0; k0 < H_; k0 += 64) {
        #pragma unroll
        for (int r = 0; r < 2; ++r) {       // A: 64x64, gather+convert
            int idx = r * 256 + tid, row = idx >> 3, seg = idx & 7;
            int tok = (t == 0) ? 1 : labels[row * 50 + (t - 1)];
            const float* s = emb + (size_t)tok * H_ + k0 + seg * 8;
            float4 f0 = *(const float4*)s;
            float4 f1 = *(const float4*)(s + 4);
            union { uint16_t h[8]; uint4 u; } p;
            p.h[0]=f2bf(f0.x); p.h[1]=f2bf(f0.y); p.h[2]=f2bf(f0.z); p.h[3]=f2bf(f0.w);
            p.h[4]=f2bf(f1.x); p.h[5]=f2bf(f1.y); p.h[6]=f2bf(f1.z); p.h[7]=f2bf(f1.w);
            *(uint4*)(Al + row * 72 + seg * 8) = p.u;
        }
        #pragma unroll
        for (int r = 0; r < 8; ++r) {       // B: 256x64
            int idx = r * 256 + tid, row = idx >> 3, seg = idx & 7;
            if (CVT) {
                const float* s = (const float*)wih + (size_t)(n0 + row) * H_ + k0 + seg * 8;
                float4 f0 = *(const float4*)s;
                float4 f1 = *(const float4*)(s + 4);
                union { uint16_t h[8]; uint4 u; } p;
                p.h[0]=f2bf(f0.x); p.h[1]=f2bf(f0.y); p.h[2]=f2bf(f0.z); p.h[3]=f2bf(f0.w);
                p.h[4]=f2bf(f1.x); p.h[5]=f2bf(f1.y); p.h[6]=f2bf(f1.z); p.h[7]=f2bf(f1.w);
                *(uint4*)(Bl + row * 72 + seg * 8) = p.u;
            } else {
                *(uint4*)(Bl + row * 72 + seg * 8) =
                    *(const uint4*)((const uint16_t*)wih + (size_t)(n0 + row) * H_ + k0 + seg * 8);
            }
        }
        __syncthreads();
        #pragma unroll
        for (int ks = 0; ks < 2; ++ks) {
            bf16x8 a[4];
            #pragma unroll
            for (int mi = 0; mi < 4; ++mi)
                a[mi] = *(const bf16x8*)(Al + (mi * 16 + l15) * 72 + ks * 32 + lhi * 8);
            #pragma unroll
            for (int nf = 0; nf < 4; ++nf) {
                bf16x8 b = *(const bf16x8*)(Bl + (w * 64 + nf * 16 + l15) * 72 + ks * 32 + lhi * 8);
                #pragma unroll
                for (int mi = 0; mi < 4; ++mi)
                    acc[mi][nf] = __builtin_amdgcn_mfma_f32_16x16x32_bf16(a[mi], b, acc[mi][nf], 0, 0, 0);
            }
        }
        __syncthreads();
    }
    float bias[4];
    #pragma unroll
    for (int nf = 0; nf < 4; ++nf) {
        int col = n0 + w * 64 + nf * 16 + l15;
        bias[nf] = b_ih[col] + b_hh[col];
    }
    #pragma unroll
    for (int mi = 0; mi < 4; ++mi)
        #pragma unroll
        for (int nf = 0; nf < 4; ++nf) {
            const int col = n0 + w * 64 + nf * 16 + l15;
            const int g = col >> 9, u = col & 511;
            const int b = mi * 16 + lhi * 4;
            union { uint16_t h[4]; ull q; } pk;
            #pragma unroll
            for (int q = 0; q < 4; ++q) pk.h[q] = f2bf(acc[mi][nf][q] + bias[nf]);
            *(ull*)(XgT + ((size_t)(t * 512 + u) * 4 + g) * 64 + b) = pk.q;
        }
}

// ---------------------------------------------------------------- K23: fused LSTM + FC
// grid 256, block 256, 66KB LDS -> 1 block/CU, ALL co-resident (no deadlock).
// Blocks 0..31: round-6 LSTM convoy (per-wave flags + sc0sc1 LLC exchange).
// Blocks 32..255: FC tiles (128x256) round-robin in t-ascending order; each
// tile spin-waits the wave flags of its max t, stages A (hs) via device-scope
// atomic loads (LLC-correct in-dispatch), B (fc_W bf16) via plain cached loads.
template<int CVT>
__global__ __launch_bounds__(256) void k23(const uint16_t* __restrict__ hx,
                                           const float* __restrict__ x,
                                           const uint16_t* __restrict__ XgT,
                                           const float* __restrict__ W_hh,
                                           uint16_t* __restrict__ hs,
                                           uint32_t* __restrict__ flags,
                                           const void* __restrict__ fcw,
                                           const float* __restrict__ fc_b,
                                           const int* __restrict__ labels,
                                           float* __restrict__ sumexp,
                                           float* __restrict__ tgtlog) {
    __shared__ uint16_t smem[64 * 520];   // 66,560 B; LSTM: Wl | FC: Al+Bl
    const int bid  = blockIdx.x;
    const int tid  = threadIdx.x;
    const int w    = tid >> 6;
    const int lane = tid & 63;
    const int l15  = lane & 15;
    const int lhi  = lane >> 4;

    if (bid < 32) {
        // ================= LSTM convoy (round-6 k2p, verbatim) =================
        uint16_t* Wl = smem;
        const int u0   = bid * 16;
        const int arow = w * 16 + l15;
        {   // W_hh slice -> bf16 LDS. LDS row c = g*16+uu <-> W row g*512+u0+uu
            const int c = tid >> 2;
            const int q = tid & 3;
            const int j = (c >> 4) * 512 + u0 + (c & 15);
            const float* src = W_hh + (size_t)j * H_ + q * 128;
            uint16_t* dst = Wl + c * 520 + q * 128;
            #pragma unroll
            for (int i = 0; i < 128; i += 8) {
                float4 f0 = *(const float4*)(src + i);
                float4 f1 = *(const float4*)(src + i + 4);
                union { uint16_t h[8]; uint4 u; } p;
                p.h[0]=f2bf(f0.x); p.h[1]=f2bf(f0.y); p.h[2]=f2bf(f0.z); p.h[3]=f2bf(f0.w);
                p.h[4]=f2bf(f1.x); p.h[5]=f2bf(f1.y); p.h[6]=f2bf(f1.z); p.h[7]=f2bf(f1.w);
                *(uint4*)(dst + i) = p.u;
            }
        }
        float cst[4];
        #pragma unroll
        for (int q = 0; q < 4; ++q)
            cst[q] = x[(size_t)(w * 16 + lhi * 4 + q) * H_ + u0 + l15];
        __syncthreads();

        for (int t = 0; t < T_; ++t) {
            ull xgp[4];
            #pragma unroll
            for (int g = 0; g < 4; ++g)
                xgp[g] = *(const ull*)(XgT + ((size_t)(t * 512 + u0 + l15) * 4 + g) * 64 + w * 16 + lhi * 4);

            u32x4 ha[16];
            if (t == 0) {
                const uint16_t* hb = hx + (size_t)arow * H_ + lhi * 8;
                #pragma unroll
                for (int ks = 0; ks < 16; ++ks)
                    ha[ks] = *(const u32x4*)(hb + ks * 32);
            } else {
                const uint32_t* fp = flags + (size_t)(t - 1) * 128 + (lane & 31) * 4 + w;
                for (;;) {
                    uint32_t fv = 1;
                    if (lane < 32) fv = ldflag(fp);
                    if (!__any((int)(fv == 0))) break;
                }
                __builtin_amdgcn_sched_barrier(0);
                const uint16_t* hb = hs + ((size_t)(t - 1) * 64 + arow) * H_ + lhi * 8;
                #pragma unroll
                for (int ks = 0; ks < 16; ++ks)
                    ldsc(ha[ks], (const uint32_t*)(hb + ks * 32));
            }
            f32x4 acc[4];
            #pragma unroll
            for (int nf = 0; nf < 4; ++nf) acc[nf] = (f32x4){0.f, 0.f, 0.f, 0.f};
            if (t != 0) { asm volatile("s_waitcnt vmcnt(8)" ::: "memory");
                          __builtin_amdgcn_sched_barrier(0); }
            #pragma unroll
            for (int ks = 0; ks < 8; ++ks) {
                union { u32x4 u; bf16x8 v; } au; au.u = ha[ks];
                #pragma unroll
                for (int nf = 0; nf < 4; ++nf) {
                    bf16x8 b = *(const bf16x8*)(Wl + (nf * 16 + l15) * 520 + ks * 32 + lhi * 8);
                    acc[nf] = __builtin_amdgcn_mfma_f32_16x16x32_bf16(au.v, b, acc[nf], 0, 0, 0);
                }
            }
            if (t != 0) { asm volatile("s_waitcnt vmcnt(0)" ::: "memory");
                          __builtin_amdgcn_sched_barrier(0); }
            #pragma unroll
            for (int ks = 8; ks < 16; ++ks) {
                union { u32x4 u; bf16x8 v; } au; au.u = ha[ks];
                #pragma unroll
                for (int nf = 0; nf < 4; ++nf) {
                    bf16x8 b = *(const bf16x8*)(Wl + (nf * 16 + l15) * 520 + ks * 32 + lhi * 8);
                    acc[nf] = __builtin_amdgcn_mfma_f32_16x16x32_bf16(au.v, b, acc[nf], 0, 0, 0);
                }
            }
            #pragma unroll
            for (int q = 0; q < 4; ++q) {
                const int b = w * 16 + lhi * 4 + q;
                float gi = acc[0][q] + bf2f((uint32_t)((xgp[0] >> (16 * q)) & 0xFFFF));
                float gf = acc[1][q] + bf2f((uint32_t)((xgp[1] >> (16 * q)) & 0xFFFF));
                float gg = acc[2][q] + bf2f((uint32_t)((xgp[2] >> (16 * q)) & 0xFFFF));
                float go = acc[3][q] + bf2f((uint32_t)((xgp[3] >> (16 * q)) & 0xFFFF));
                float si = 1.f / (1.f + __expf(-gi));
                float sf = 1.f / (1.f + __expf(-gf));
                float tg = tanhf(gg);
                float so = 1.f / (1.f + __expf(-go));
                float cc = sf * cst[q] + si * tg;
                cst[q] = cc;
                stsh(hs + (size_t)(t * 64 + b) * H_ + u0 + l15, (uint32_t)f2bf(so * tanhf(cc)));
            }
            asm volatile("s_waitcnt vmcnt(0)" ::: "memory");
            if (lane == 0) stflag(flags + (size_t)t * 128 + bid * 4 + w, (uint32_t)(t + 1));
        }
        return;
    }

    // ================= FC consumer (tile 128x256, BK=64, 4 waves) =================
    uint16_t* Al = smem;              // [128*72]
    uint16_t* Bl = smem + 128 * 72;   // [256*72]
    int ready_t = -1;
    for (int id = bid - 32; id < NTILE; id += NFC) {
        const int m0 = (id / 125) * 128;
        const int v0 = (id % 125) * 256;
        const int mt = (m0 + 127) >> 6;
        const int maxt = mt > 50 ? 50 : mt;
        if (maxt > ready_t) {
            if (tid < 128)
                while (ldflag(flags + (size_t)maxt * 128 + tid) == 0)
                    __builtin_amdgcn_s_sleep(8);
            ready_t = maxt;
        }
        __syncthreads();   // flags seen + smem free (prev tile's MFMA done)

        f32x4 acc[8][4];
        #pragma unroll
        for (int mi = 0; mi < 8; ++mi)
            #pragma unroll
            for (int nf = 0; nf < 4; ++nf) acc[mi][nf] = (f32x4){0.f, 0.f, 0.f, 0.f};

        for (int k0 = 0; k0 < H_; k0 += 64) {
            #pragma unroll
            for (int r = 0; r < 4; ++r) {     // A: 128x64, LLC atomic loads
                int idx = r * 256 + tid, row = idx >> 3, seg = idx & 7;
                int grow = m0 + row; if (grow >= R_) grow = R_ - 1;
                const ull* p = (const ull*)(hs + (size_t)grow * H_ + k0 + seg * 8);
                union { ull q[2]; uint4 u; } d;
                d.q[0] = __hip_atomic_load(p,     __ATOMIC_RELAXED, __HIP_MEMORY_SCOPE_AGENT);
                d.q[1] = __hip_atomic_load(p + 1, __ATOMIC_RELAXED, __HIP_MEMORY_SCOPE_AGENT);
                *(uint4*)(Al + row * 72 + seg * 8) = d.u;
            }
            #pragma unroll
            for (int r = 0; r < 8; ++r) {     // B: 256x64
                int idx = r * 256 + tid, row = idx >> 3, seg = idx & 7;
                if (CVT) {
                    const float* s = (const float*)fcw + (size_t)(v0 + row) * H_ + k0 + seg * 8;
                    float4 f0 = *(const float4*)s;
                    float4 f1 = *(const float4*)(s + 4);
                    union { uint16_t h[8]; uint4 u; } p;
                    p.h[0]=f2bf(f0.x); p.h[1]=f2bf(f0.y); p.h[2]=f2bf(f0.z); p.h[3]=f2bf(f0.w);
                    p.h[4]=f2bf(f1.x); p.h[5]=f2bf(f1.y); p.h[6]=f2bf(f1.z); p.h[7]=f2bf(f1.w);
                    *(uint4*)(Bl + row * 72 + seg * 8) = p.u;
                } else {
                    *(uint4*)(Bl + row * 72 + seg * 8) =
                        *(const uint4*)((const uint16_t*)fcw + (size_t)(v0 + row) * H_ + k0 + seg * 8);
                }
            }
            __syncthreads();
            #pragma unroll
            for (int ks = 0; ks < 2; ++ks) {
                bf16x8 a[8];
                #pragma unroll
                for (int mi = 0; mi < 8; ++mi)
                    a[mi] = *(const bf16x8*)(Al + (mi * 16 + l15) * 72 + ks * 32 + lhi * 8);
                #pragma unroll
                for (int nf = 0; nf < 4; ++nf) {
                    bf16x8 b = *(const bf16x8*)(Bl + (w * 64 + nf * 16 + l15) * 72 + ks * 32 + lhi * 8);
                    #pragma unroll
                    for (int mi = 0; mi < 8; ++mi)
                        acc[mi][nf] = __builtin_amdgcn_mfma_f32_16x16x32_bf16(a[mi], b, acc[mi][nf], 0, 0, 0);
                }
            }
            __syncthreads();
        }
        // epilogue: bias + exp-sum (16-lane shuffle reduce) + target-logit pick
        float bias[4];
        #pragma unroll
        for (int nf = 0; nf < 4; ++nf) bias[nf] = fc_b[v0 + w * 64 + nf * 16 + l15];
        #pragma unroll
        for (int mi = 0; mi < 8; ++mi) {
            #pragma unroll
            for (int q = 0; q < 4; ++q) {
                const int r = m0 + mi * 16 + lhi * 4 + q;
                if (r >= R_) continue;
                const int t = r >> 6, b = r & 63;
                const int tgt = (t < 50) ? labels[b * 50 + t] : 2;
                float lsum = 0.f;
                #pragma unroll
                for (int nf = 0; nf < 4; ++nf) {
                    const int v = v0 + w * 64 + nf * 16 + l15;
                    float lg = acc[mi][nf][q] + bias[nf];
                    lsum += __expf(lg);
                    if (v == tgt) tgtlog[r] = lg;
                }
                lsum += __shfl_xor(lsum, 1, 16);
                lsum += __shfl_xor(lsum, 2, 16);
                lsum += __shfl_xor(lsum, 4, 16);
                lsum += __shfl_xor(lsum, 8, 16);
                if (l15 == 0) atomicAdd(&sumexp[r], lsum);
            }
        }
        __syncthreads();
    }
}

// ---------------------------------------------------------------- K4: loss
__global__ __launch_bounds__(256) void k4_loss(const float* __restrict__ sumexp,
                                               const float* __restrict__ tgtlog,
                                               float* __restrict__ out) {
    __shared__ float red[256];
    float s = 0.f;
    for (int r = threadIdx.x; r < R_; r += 256) s += logf(sumexp[r]) - tgtlog[r];
    red[threadIdx.x] = s;
    __syncthreads();
    for (int st = 128; st > 0; st >>= 1) {
        if (threadIdx.x < st) red[threadIdx.x] += red[threadIdx.x + st];
        __syncthreads();
    }
    if (threadIdx.x == 0) out[0] = red[0] / 64.0f;
}

// ----------------------------------------------------------------
extern "C" void kernel_launch(void* const* d_in, const int* in_sizes, int n_in,
                              void* d_out, int out_size, void* d_ws, size_t ws_size,
                              hipStream_t stream) {
    const float* x      = (const float*)d_in[0];
    const int*   labels = (const int*)d_in[1];
    const float* emb    = (const float*)d_in[2];
    const float* W_ih   = (const float*)d_in[3];
    const float* W_hh   = (const float*)d_in[4];
    const float* b_ih   = (const float*)d_in[5];
    const float* b_hh   = (const float*)d_in[6];
    const float* fc_W   = (const float*)d_in[7];
    const float* fc_b   = (const float*)d_in[8];
    float* out = (float*)d_out;

    char* p = (char*)d_ws;
    uint16_t* XgT    = (uint16_t*)p;  p += (size_t)T_ * 512 * 4 * 64 * 2;  // 13.4 MB
    uint16_t* hsb    = (uint16_t*)p;  p += (size_t)R_ * H_ * 2;            // 3.3 MB
    uint16_t* hx     = (uint16_t*)p;  p += (size_t)B_ * H_ * 2;
    float*    sumexp = (float*)p;     p += (size_t)R_ * 4;
    float*    tgtl   = (float*)p;     p += (size_t)R_ * 4;
    uint32_t* flags  = (uint32_t*)p;  p += (size_t)T_ * 128 * 4 + 256;     // 26 KB
    uint16_t* fcwb   = (uint16_t*)p;  p += (size_t)V_ * H_ * 2;            // 32.8 MB
    uint16_t* wihb   = (uint16_t*)p;  p += (size_t)G4_ * H_ * 2;           // 2.1 MB
    const bool pre = ((size_t)(p - (char*)d_ws) <= ws_size);

    k0_init<<<128, 256, 0, stream>>>(x, hx, sumexp, flags);
    if (pre) {
        kcvt<<<8000, 256, 0, stream>>>(fc_W, fcwb, (V_ * H_) / 8);
        kcvt<<<512, 256, 0, stream>>>(W_ih, wihb, (G4_ * H_) / 8);
        k1_mfma<0><<<dim3(8, 51), 256, 0, stream>>>(labels, emb, wihb, b_ih, b_hh, XgT);
        k23<0><<<256, 256, 0, stream>>>(hx, x, XgT, W_hh, hsb, flags,
                                        fcwb, fc_b, labels, sumexp, tgtl);
    } else {
        k1_mfma<1><<<dim3(8, 51), 256, 0, stream>>>(labels, emb, W_ih, b_ih, b_hh, XgT);
        k23<1><<<256, 256, 0, stream>>>(hx, x, XgT, W_hh, hsb, flags,
                                        fc_W, fc_b, labels, sumexp, tgtl);
    }
    k4_loss<<<1, 256, 0, stream>>>(sumexp, tgtl, out);
}

// Round 9
// 546.892 us; speedup vs baseline: 1.2784x; 1.2784x over previous
//
#include <hip/hip_runtime.h>
#include <cstddef>
#include <cstdint>

#define B_  64
#define T_  51
#define H_  512
#define G4_ 2048
#define V_  32000
#define R_  (T_ * B_)   // 3264

typedef __attribute__((ext_vector_type(8))) short bf16x8;
typedef __attribute__((ext_vector_type(4))) float f32x4;
typedef __attribute__((ext_vector_type(4))) unsigned int u32x4;
typedef unsigned long long ull;

__device__ __forceinline__ uint16_t f2bf(float f) {   // RNE float->bf16
    uint32_t u = __float_as_uint(f);
    u += 0x7FFFu + ((u >> 16) & 1u);
    return (uint16_t)(u >> 16);
}
__device__ __forceinline__ float bf2f(uint32_t h) { return __uint_as_float(h << 16); }

// LLC-coherent ops (bypass L1+L2; correct across XCDs within a dispatch)
__device__ __forceinline__ void ldsc(u32x4& d, const uint32_t* p) {
    asm volatile("global_load_dwordx4 %0, %1, off sc0 sc1" : "=v"(d) : "v"(p));
}
__device__ __forceinline__ uint32_t ldflag(const uint32_t* p) {
    uint32_t v;
    asm volatile("global_load_dword %0, %1, off sc0 sc1\n\ts_waitcnt vmcnt(0)"
                 : "=v"(v) : "v"(p));
    return v;
}
__device__ __forceinline__ void stflag(uint32_t* p, uint32_t v) {
    asm volatile("global_store_dword %0, %1, off sc0 sc1" :: "v"(p), "v"(v) : "memory");
}
__device__ __forceinline__ void stq(uint16_t* p, ull v) {   // 8B store, LLC
    asm volatile("global_store_dwordx2 %0, %1, off sc0 sc1" :: "v"(p), "v"(v) : "memory");
}

// async global->LDS, 16B per lane, linear dest
__device__ __forceinline__ void gl_lds16(const void* g, void* l) {
    __builtin_amdgcn_global_load_lds((const __attribute__((address_space(1))) void*)g,
                                     (__attribute__((address_space(3))) void*)l, 16, 0, 0);
}

// ---------------------------------------------------------------- K0: init
__global__ __launch_bounds__(256) void k0_init(const float* __restrict__ x,
                                               uint16_t* __restrict__ hx,
                                               float* __restrict__ sumexp,
                                               uint32_t* __restrict__ flags) {
    int i = blockIdx.x * 256 + threadIdx.x;      // 0..32767
    if (i < B_ * H_) hx[i] = f2bf(x[i]);
    if (i < R_) sumexp[i] = 0.f;
    if (i < T_ * 128) flags[i] = 0;
}

// ---------------------------------------------------------------- Kcvt: f32 -> bf16
__global__ __launch_bounds__(256) void kcvt(const float* __restrict__ src,
                                            uint16_t* __restrict__ dst, int n8) {
    int i = blockIdx.x * 256 + threadIdx.x;
    if (i >= n8) return;
    const float4* s = (const float4*)src + (size_t)i * 2;
    float4 f0 = s[0], f1 = s[1];
    union { uint16_t h[8]; uint4 u; } p;
    p.h[0]=f2bf(f0.x); p.h[1]=f2bf(f0.y); p.h[2]=f2bf(f0.z); p.h[3]=f2bf(f0.w);
    p.h[4]=f2bf(f1.x); p.h[5]=f2bf(f1.y); p.h[6]=f2bf(f1.z); p.h[7]=f2bf(f1.w);
    ((uint4*)dst)[i] = p.u;
}

// ---------------------------------------------------------------- K1: Xg GEMM (bf16 MFMA)
// Xg row-major bf16: Xg[r*2048 + col] = bf16( emb[tok(r)].W_ih[col] + b_ih + b_hh )
template<int CVT>
__global__ __launch_bounds__(256, 2) void k1_mfma(const int* __restrict__ labels,
                                                  const float* __restrict__ emb,
                                                  const void* __restrict__ wih,
                                                  const float* __restrict__ b_ih,
                                                  const float* __restrict__ b_hh,
                                                  uint16_t* __restrict__ Xg) {
    __shared__ uint16_t Al[64 * 72];
    __shared__ uint16_t Bl[256 * 72];
    const int t    = blockIdx.y;
    const int n0   = blockIdx.x * 256;
    const int tid  = threadIdx.x;
    const int w    = tid >> 6;
    const int lane = tid & 63;
    const int l15  = lane & 15;
    const int lhi  = lane >> 4;

    f32x4 acc[4][4];
    #pragma unroll
    for (int mi = 0; mi < 4; ++mi)
        #pragma unroll
        for (int nf = 0; nf < 4; ++nf) acc[mi][nf] = (f32x4){0.f, 0.f, 0.f, 0.f};

    for (int k0 = 0; k0 < H_; k0 += 64) {
        #pragma unroll
        for (int r = 0; r < 2; ++r) {       // A: 64x64, gather+convert
            int idx = r * 256 + tid, row = idx >> 3, seg = idx & 7;
            int tok = (t == 0) ? 1 : labels[row * 50 + (t - 1)];
            const float* s = emb + (size_t)tok * H_ + k0 + seg * 8;
            float4 f0 = *(const float4*)s;
            float4 f1 = *(const float4*)(s + 4);
            union { uint16_t h[8]; uint4 u; } p;
            p.h[0]=f2bf(f0.x); p.h[1]=f2bf(f0.y); p.h[2]=f2bf(f0.z); p.h[3]=f2bf(f0.w);
            p.h[4]=f2bf(f1.x); p.h[5]=f2bf(f1.y); p.h[6]=f2bf(f1.z); p.h[7]=f2bf(f1.w);
            *(uint4*)(Al + row * 72 + seg * 8) = p.u;
        }
        #pragma unroll
        for (int r = 0; r < 8; ++r) {       // B: 256x64
            int idx = r * 256 + tid, row = idx >> 3, seg = idx & 7;
            if (CVT) {
                const float* s = (const float*)wih + (size_t)(n0 + row) * H_ + k0 + seg * 8;
                float4 f0 = *(const float4*)s;
                float4 f1 = *(const float4*)(s + 4);
                union { uint16_t h[8]; uint4 u; } p;
                p.h[0]=f2bf(f0.x); p.h[1]=f2bf(f0.y); p.h[2]=f2bf(f0.z); p.h[3]=f2bf(f0.w);
                p.h[4]=f2bf(f1.x); p.h[5]=f2bf(f1.y); p.h[6]=f2bf(f1.z); p.h[7]=f2bf(f1.w);
                *(uint4*)(Bl + row * 72 + seg * 8) = p.u;
            } else {
                *(uint4*)(Bl + row * 72 + seg * 8) =
                    *(const uint4*)((const uint16_t*)wih + (size_t)(n0 + row) * H_ + k0 + seg * 8);
            }
        }
        __syncthreads();
        #pragma unroll
        for (int ks = 0; ks < 2; ++ks) {
            bf16x8 a[4];
            #pragma unroll
            for (int mi = 0; mi < 4; ++mi)
                a[mi] = *(const bf16x8*)(Al + (mi * 16 + l15) * 72 + ks * 32 + lhi * 8);
            #pragma unroll
            for (int nf = 0; nf < 4; ++nf) {
                bf16x8 b = *(const bf16x8*)(Bl + (w * 64 + nf * 16 + l15) * 72 + ks * 32 + lhi * 8);
                #pragma unroll
                for (int mi = 0; mi < 4; ++mi)
                    acc[mi][nf] = __builtin_amdgcn_mfma_f32_16x16x32_bf16(a[mi], b, acc[mi][nf], 0, 0, 0);
            }
        }
        __syncthreads();
    }
    float bias[4];
    #pragma unroll
    for (int nf = 0; nf < 4; ++nf) {
        int col = n0 + w * 64 + nf * 16 + l15;
        bias[nf] = b_ih[col] + b_hh[col];
    }
    #pragma unroll
    for (int mi = 0; mi < 4; ++mi)
        #pragma unroll
        for (int nf = 0; nf < 4; ++nf) {
            const int col = n0 + w * 64 + nf * 16 + l15;
            #pragma unroll
            for (int q = 0; q < 4; ++q) {
                const int r = t * 64 + mi * 16 + lhi * 4 + q;
                Xg[(size_t)r * G4_ + col] = f2bf(acc[mi][nf][q] + bias[nf]);
            }
        }
}

// ---------------------------------------------------------------- K2p: persistent LSTM
// 32 blocks x 4 waves; block owns 16 units; wave w owns batch rows w*16..+15.
// SWAPPED MFMA: acc[g] = mfma(A=W_hh frag, B=h frag) -> D rows=units, cols=batch
// -> lane owns 4 CONSECUTIVE units of one row: h-store = 1 dwordx2; Xg biases
// are 8B row-major loads. Exchange split lo/hi (units 0-255 / 256-511):
// poll lo flags -> issue lo loads -> poll hi (drains lo) -> issue hi ->
// MFMA lo -> vmcnt(0) -> MFMA hi. No intra-loop __syncthreads.
__global__ __launch_bounds__(256, 1) void k2p(const uint16_t* __restrict__ hx,
                                              const float* __restrict__ x,
                                              const uint16_t* __restrict__ Xg,
                                              const float* __restrict__ W_hh,
                                              uint16_t* __restrict__ hs,
                                              uint32_t* __restrict__ flags) {
    __shared__ uint16_t Wl[64 * 520];
    const int tid  = threadIdx.x;
    const int bid  = blockIdx.x;
    const int u0   = bid * 16;
    const int w    = tid >> 6;
    const int lane = tid & 63;
    const int l15  = lane & 15;
    const int lhi  = lane >> 4;
    const int arow = w * 16 + l15;      // this lane's batch row

    {   // W_hh slice -> bf16 LDS. LDS row c = g*16+uu <-> W row g*512+u0+uu
        const int c = tid >> 2;
        const int q = tid & 3;
        const int j = (c >> 4) * 512 + u0 + (c & 15);
        const float* src = W_hh + (size_t)j * H_ + q * 128;
        uint16_t* dst = Wl + c * 520 + q * 128;
        #pragma unroll
        for (int i = 0; i < 128; i += 8) {
            float4 f0 = *(const float4*)(src + i);
            float4 f1 = *(const float4*)(src + i + 4);
            union { uint16_t h[8]; uint4 u; } p;
            p.h[0]=f2bf(f0.x); p.h[1]=f2bf(f0.y); p.h[2]=f2bf(f0.z); p.h[3]=f2bf(f0.w);
            p.h[4]=f2bf(f1.x); p.h[5]=f2bf(f1.y); p.h[6]=f2bf(f1.z); p.h[7]=f2bf(f1.w);
            *(uint4*)(dst + i) = p.u;
        }
    }
    // c-state: this lane's batch row, units u0+lhi*4 .. +3 (float4)
    float4 cst = *(const float4*)(x + (size_t)arow * H_ + u0 + lhi * 4);
    __syncthreads();                    // Wl ready (read-only afterwards)

    for (int t = 0; t < T_; ++t) {
        // gate biases: 4 x 8B from row-major bf16 Xg (race-free, cached)
        ull xgp[4];
        #pragma unroll
        for (int g = 0; g < 4; ++g)
            xgp[g] = *(const ull*)(Xg + (size_t)(t * 64 + arow) * G4_ + g * 512 + u0 + lhi * 4);

        u32x4 ha[16];
        if (t == 0) {
            const uint16_t* hb = hx + (size_t)arow * H_ + lhi * 8;
            #pragma unroll
            for (int ks = 0; ks < 16; ++ks)
                ha[ks] = *(const u32x4*)(hb + ks * 32);
        } else {
            const uint16_t* hb = hs + ((size_t)(t - 1) * 64 + arow) * H_ + lhi * 8;
            // ---- lo half: blocks 0-15 (units 0-255) ----
            const uint32_t* fpl = flags + (size_t)(t - 1) * 128 + (lane & 15) * 4 + w;
            for (;;) {
                uint32_t fv = 1;
                if (lane < 16) fv = ldflag(fpl);
                if (!__any((int)(fv == 0))) break;
            }
            __builtin_amdgcn_sched_barrier(0);
            #pragma unroll
            for (int ks = 0; ks < 8; ++ks)
                ldsc(ha[ks], (const uint32_t*)(hb + ks * 32));
            // ---- hi half: blocks 16-31 (units 256-511); poll drains lo data ----
            const uint32_t* fph = flags + (size_t)(t - 1) * 128 + (16 + (lane & 15)) * 4 + w;
            for (;;) {
                uint32_t fv = 1;
                if (lane < 16) fv = ldflag(fph);
                if (!__any((int)(fv == 0))) break;
            }
            __builtin_amdgcn_sched_barrier(0);
            #pragma unroll
            for (int ks = 8; ks < 16; ++ks)
                ldsc(ha[ks], (const uint32_t*)(hb + ks * 32));
        }
        f32x4 acc[4];
        #pragma unroll
        for (int g = 0; g < 4; ++g) acc[g] = (f32x4){0.f, 0.f, 0.f, 0.f};
        if (t != 0) { asm volatile("s_waitcnt vmcnt(8)" ::: "memory");
                      __builtin_amdgcn_sched_barrier(0); }
        #pragma unroll
        for (int ks = 0; ks < 8; ++ks) {     // MFMA lo: A=W, B=h
            union { u32x4 u; bf16x8 v; } bu; bu.u = ha[ks];
            #pragma unroll
            for (int g = 0; g < 4; ++g) {
                bf16x8 a = *(const bf16x8*)(Wl + (g * 16 + l15) * 520 + ks * 32 + lhi * 8);
                acc[g] = __builtin_amdgcn_mfma_f32_16x16x32_bf16(a, bu.v, acc[g], 0, 0, 0);
            }
        }
        if (t != 0) { asm volatile("s_waitcnt vmcnt(0)" ::: "memory");
                      __builtin_amdgcn_sched_barrier(0); }
        #pragma unroll
        for (int ks = 8; ks < 16; ++ks) {    // MFMA hi
            union { u32x4 u; bf16x8 v; } bu; bu.u = ha[ks];
            #pragma unroll
            for (int g = 0; g < 4; ++g) {
                bf16x8 a = *(const bf16x8*)(Wl + (g * 16 + l15) * 520 + ks * 32 + lhi * 8);
                acc[g] = __builtin_amdgcn_mfma_f32_16x16x32_bf16(a, bu.v, acc[g], 0, 0, 0);
            }
        }
        // D: row = unit u0+lhi*4+q, col = batch arow  ->  4 consecutive units/lane
        union { uint16_t h[4]; ull q8; } hv;
        #pragma unroll
        for (int q = 0; q < 4; ++q) {
            float gi = acc[0][q] + bf2f((uint32_t)((xgp[0] >> (16 * q)) & 0xFFFF));
            float gf = acc[1][q] + bf2f((uint32_t)((xgp[1] >> (16 * q)) & 0xFFFF));
            float gg = acc[2][q] + bf2f((uint32_t)((xgp[2] >> (16 * q)) & 0xFFFF));
            float go = acc[3][q] + bf2f((uint32_t)((xgp[3] >> (16 * q)) & 0xFFFF));
            float si = 1.f / (1.f + __expf(-gi));
            float sf = 1.f / (1.f + __expf(-gf));
            float tg = tanhf(gg);
            float so = 1.f / (1.f + __expf(-go));
            float cc = sf * cst[q] + si * tg;
            cst[q] = cc;
            hv.h[q] = f2bf(so * tanhf(cc));
        }
        stq(hs + (size_t)(t * 64 + arow) * H_ + u0 + lhi * 4, hv.q8);
        asm volatile("s_waitcnt vmcnt(0)" ::: "memory");   // data at LLC
        if (lane == 0) stflag(flags + (size_t)t * 128 + bid * 4 + w, (uint32_t)(t + 1));
    }
}

// ---------------------------------------------------------------- K3: FC + lse (bf16 MFMA)
// m97-style: tile 128x256, BK=64, 8 waves. global_load_lds width 16,
// XOR-swizzled source+read (T2): conflict-free. 1D grid, bijective XCD swizzle.
template<int CVT>
__global__ __launch_bounds__(512, 4) void k3_mfma(const uint16_t* __restrict__ hsb,
                                                  const void* __restrict__ fcw,
                                                  const float* __restrict__ fc_b,
                                                  const int* __restrict__ labels,
                                                  float* __restrict__ sumexp,
                                                  float* __restrict__ tgtlog) {
    __shared__ uint16_t Al[128 * 64];   // 16 KB
    __shared__ uint16_t Bl[256 * 64];   // 32 KB
    const int flat = blockIdx.x;        // 3250 = 8*406+2: xcd 0,1 get 407
    const int xcd  = flat & 7;
    const int slot = flat >> 3;
    const int work = (xcd < 2 ? xcd * 407 : 814 + (xcd - 2) * 406) + slot;
    const int m0   = (work % 26) * 128;
    const int v0   = (work / 26) * 256;
    const int tid  = threadIdx.x;
    const int w    = tid >> 6;
    const int lane = tid & 63;
    const int l15  = lane & 15;
    const int lhi  = lane >> 4;
    const int wm   = w >> 2;
    const int wn   = w & 3;

    f32x4 acc[4][4];
    #pragma unroll
    for (int mi = 0; mi < 4; ++mi)
        #pragma unroll
        for (int nf = 0; nf < 4; ++nf) acc[mi][nf] = (f32x4){0.f, 0.f, 0.f, 0.f};

    const int lrow = lane >> 3;                 // 0..7 within 8-row group
    const int segp = (lane & 7) ^ lrow;         // pre-swizzled source seg

    for (int k0 = 0; k0 < H_; k0 += 64) {
        #pragma unroll
        for (int r = 0; r < 2; ++r) {           // A: 128x64
            const int g = w * 2 + r, row0 = g * 8;
            int grow = m0 + row0 + lrow; if (grow >= R_) grow = R_ - 1;
            gl_lds16(hsb + (size_t)grow * H_ + k0 + segp * 8, Al + row0 * 64);
        }
        if (CVT == 0) {
            #pragma unroll
            for (int r = 0; r < 4; ++r) {       // B: 256x64
                const int g = w * 4 + r, row0 = g * 8;
                gl_lds16((const uint16_t*)fcw + (size_t)(v0 + row0 + lrow) * H_ + k0 + segp * 8,
                         Bl + row0 * 64);
            }
        } else {
            #pragma unroll
            for (int r = 0; r < 4; ++r) {       // reg-stage + convert, swizzled write
                int idx = r * 512 + tid, row = idx >> 3, seg = idx & 7;
                const float* s = (const float*)fcw + (size_t)(v0 + row) * H_ + k0 + seg * 8;
                float4 f0 = *(const float4*)s;
                float4 f1 = *(const float4*)(s + 4);
                union { uint16_t h[8]; uint4 u; } p;
                p.h[0]=f2bf(f0.x); p.h[1]=f2bf(f0.y); p.h[2]=f2bf(f0.z); p.h[3]=f2bf(f0.w);
                p.h[4]=f2bf(f1.x); p.h[5]=f2bf(f1.y); p.h[6]=f2bf(f1.z); p.h[7]=f2bf(f1.w);
                *(uint4*)(Bl + row * 64 + (seg ^ (row & 7)) * 8) = p.u;
            }
        }
        __syncthreads();
        #pragma unroll
        for (int ks = 0; ks < 2; ++ks) {
            bf16x8 a[4];
            #pragma unroll
            for (int mi = 0; mi < 4; ++mi) {
                const int ar = wm * 64 + mi * 16 + l15;
                a[mi] = *(const bf16x8*)((const char*)Al + ar * 128 +
                        ((ks * 64 + lhi * 16) ^ ((ar & 7) << 4)));
            }
            #pragma unroll
            for (int nf = 0; nf < 4; ++nf) {
                const int br = wn * 64 + nf * 16 + l15;
                bf16x8 b = *(const bf16x8*)((const char*)Bl + br * 128 +
                           ((ks * 64 + lhi * 16) ^ ((br & 7) << 4)));
                #pragma unroll
                for (int mi = 0; mi < 4; ++mi)
                    acc[mi][nf] = __builtin_amdgcn_mfma_f32_16x16x32_bf16(a[mi], b, acc[mi][nf], 0, 0, 0);
            }
        }
        __syncthreads();
    }
    float bias[4];
    #pragma unroll
    for (int nf = 0; nf < 4; ++nf) bias[nf] = fc_b[v0 + wn * 64 + nf * 16 + l15];
    #pragma unroll
    for (int mi = 0; mi < 4; ++mi) {
        #pragma unroll
        for (int q = 0; q < 4; ++q) {
            const int r = m0 + wm * 64 + mi * 16 + lhi * 4 + q;
            if (r >= R_) continue;
            const int t = r >> 6, b = r & 63;
            const int tgt = (t < 50) ? labels[b * 50 + t] : 2;
            float lsum = 0.f;
            #pragma unroll
            for (int nf = 0; nf < 4; ++nf) {
                const int v = v0 + wn * 64 + nf * 16 + l15;
                float lg = acc[mi][nf][q] + bias[nf];
                lsum += __expf(lg);
                if (v == tgt) tgtlog[r] = lg;
            }
            lsum += __shfl_xor(lsum, 1, 16);
            lsum += __shfl_xor(lsum, 2, 16);
            lsum += __shfl_xor(lsum, 4, 16);
            lsum += __shfl_xor(lsum, 8, 16);
            if (l15 == 0) atomicAdd(&sumexp[r], lsum);
        }
    }
}

// ---------------------------------------------------------------- K4: loss
__global__ __launch_bounds__(256) void k4_loss(const float* __restrict__ sumexp,
                                               const float* __restrict__ tgtlog,
                                               float* __restrict__ out) {
    __shared__ float red[256];
    float s = 0.f;
    for (int r = threadIdx.x; r < R_; r += 256) s += logf(sumexp[r]) - tgtlog[r];
    red[threadIdx.x] = s;
    __syncthreads();
    for (int st = 128; st > 0; st >>= 1) {
        if (threadIdx.x < st) red[threadIdx.x] += red[threadIdx.x + st];
        __syncthreads();
    }
    if (threadIdx.x == 0) out[0] = red[0] / 64.0f;
}

// ----------------------------------------------------------------
extern "C" void kernel_launch(void* const* d_in, const int* in_sizes, int n_in,
                              void* d_out, int out_size, void* d_ws, size_t ws_size,
                              hipStream_t stream) {
    const float* x      = (const float*)d_in[0];
    const int*   labels = (const int*)d_in[1];
    const float* emb    = (const float*)d_in[2];
    const float* W_ih   = (const float*)d_in[3];
    const float* W_hh   = (const float*)d_in[4];
    const float* b_ih   = (const float*)d_in[5];
    const float* b_hh   = (const float*)d_in[6];
    const float* fc_W   = (const float*)d_in[7];
    const float* fc_b   = (const float*)d_in[8];
    float* out = (float*)d_out;

    char* p = (char*)d_ws;
    uint16_t* Xg     = (uint16_t*)p;  p += (size_t)R_ * G4_ * 2;           // 13.4 MB
    uint16_t* hsb    = (uint16_t*)p;  p += (size_t)R_ * H_ * 2;            // 3.3 MB
    uint16_t* hx     = (uint16_t*)p;  p += (size_t)B_ * H_ * 2;
    float*    sumexp = (float*)p;     p += (size_t)R_ * 4;
    float*    tgtl   = (float*)p;     p += (size_t)R_ * 4;
    uint32_t* flags  = (uint32_t*)p;  p += (size_t)T_ * 128 * 4 + 256;     // 26 KB
    uint16_t* fcwb   = (uint16_t*)p;  p += (size_t)V_ * H_ * 2;            // 32.8 MB
    uint16_t* wihb   = (uint16_t*)p;  p += (size_t)G4_ * H_ * 2;           // 2.1 MB
    const bool pre = ((size_t)(p - (char*)d_ws) <= ws_size);

    k0_init<<<128, 256, 0, stream>>>(x, hx, sumexp, flags);
    if (pre) {
        kcvt<<<8000, 256, 0, stream>>>(fc_W, fcwb, (V_ * H_) / 8);
        kcvt<<<512, 256, 0, stream>>>(W_ih, wihb, (G4_ * H_) / 8);
        k1_mfma<0><<<dim3(8, 51), 256, 0, stream>>>(labels, emb, wihb, b_ih, b_hh, Xg);
    } else {
        k1_mfma<1><<<dim3(8, 51), 256, 0, stream>>>(labels, emb, W_ih, b_ih, b_hh, Xg);
    }
    k2p<<<32, 256, 0, stream>>>(hx, x, Xg, W_hh, hsb, flags);
    if (pre) k3_mfma<0><<<3250, 512, 0, stream>>>(hsb, fcwb, fc_b, labels, sumexp, tgtl);
    else     k3_mfma<1><<<3250, 512, 0, stream>>>(hsb, fc_W, fc_b, labels, sumexp, tgtl);
    k4_loss<<<1, 256, 0, stream>>>(sumexp, tgtl, out);
}

// Round 10
// 508.141 us; speedup vs baseline: 1.3758x; 1.0763x over previous
//
#include <hip/hip_runtime.h>
#include <cstddef>
#include <cstdint>

#define B_  64
#define T_  51
#define H_  512
#define G4_ 2048
#define V_  32000
#define R_  (T_ * B_)   // 3264
#define NHF (T_ * 128)  // h-flags; xg-flags at [NHF, NHF+512)

typedef __attribute__((ext_vector_type(8))) short bf16x8;
typedef __attribute__((ext_vector_type(4))) float f32x4;
typedef __attribute__((ext_vector_type(4))) unsigned int u32x4;
typedef unsigned long long ull;

__device__ __forceinline__ uint16_t f2bf(float f) {   // RNE float->bf16
    uint32_t u = __float_as_uint(f);
    u += 0x7FFFu + ((u >> 16) & 1u);
    return (uint16_t)(u >> 16);
}
__device__ __forceinline__ float bf2f(uint32_t h) { return __uint_as_float(h << 16); }

// LLC-coherent ops (bypass L1+L2; correct across XCDs within a dispatch)
__device__ __forceinline__ void ldsc(u32x4& d, const uint32_t* p) {
    asm volatile("global_load_dwordx4 %0, %1, off sc0 sc1" : "=v"(d) : "v"(p));
}
__device__ __forceinline__ void ldq2(ull& d, const uint16_t* p) {
    asm volatile("global_load_dwordx2 %0, %1, off sc0 sc1" : "=v"(d) : "v"(p));
}
__device__ __forceinline__ uint32_t ldflag(const uint32_t* p) {
    uint32_t v;
    asm volatile("global_load_dword %0, %1, off sc0 sc1\n\ts_waitcnt vmcnt(0)"
                 : "=v"(v) : "v"(p));
    return v;
}
__device__ __forceinline__ void stflag(uint32_t* p, uint32_t v) {
    asm volatile("global_store_dword %0, %1, off sc0 sc1" :: "v"(p), "v"(v) : "memory");
}
__device__ __forceinline__ void stsh(uint16_t* p, uint32_t v) {
    asm volatile("global_store_short %0, %1, off sc0 sc1" :: "v"(p), "v"(v) : "memory");
}
__device__ __forceinline__ void stq(uint16_t* p, ull v) {
    asm volatile("global_store_dwordx2 %0, %1, off sc0 sc1" :: "v"(p), "v"(v) : "memory");
}

// async global->LDS, 16B per lane, linear dest
__device__ __forceinline__ void gl_lds16(const void* g, void* l) {
    __builtin_amdgcn_global_load_lds((const __attribute__((address_space(1))) void*)g,
                                     (__attribute__((address_space(3))) void*)l, 16, 0, 0);
}

// ---------------------------------------------------------------- K0: init
// sumexp = 0; all flags = 0 (per call: replay-safe)
__global__ __launch_bounds__(256) void k0_init(float* __restrict__ sumexp,
                                               uint32_t* __restrict__ flags) {
    int i = blockIdx.x * 256 + threadIdx.x;
    if (i < R_) sumexp[i] = 0.f;
    if (i < NHF + 512) flags[i] = 0;
}

// ---------------------------------------------------------------- K12p: fused prologue + LSTM
// grid 256 x 256 thr, 66KB LDS (all co-resident; no cross deps from workers).
// Blocks 0..31: round-6 LSTM convoy. Per step t: poll {32 h-flags(t-1) on
// lanes 0-31} U {8 Xg-tile-flags(t) on lanes 32-39} in ONE loop -> 16 sc0sc1
// h-loads + 4 sc0sc1 xgp loads -> vmcnt(12)/MFMA-lo/vmcnt(0)/MFMA-hi -> gates
// -> 4 stsh -> vmcnt(0) -> flag. t=0: A-frags converted from x in-register.
// Blocks 32..255: 408 k1 tiles (t-ascending; sc0sc1 XgT stores + per-tile
// flag), then stream-convert fc_W -> bf16. NO polling by workers.
template<int DOFC>
__global__ __launch_bounds__(256) void k12p(const float* __restrict__ x,
                                            const int* __restrict__ labels,
                                            const float* __restrict__ emb,
                                            const float* __restrict__ W_ih,
                                            const float* __restrict__ b_ih,
                                            const float* __restrict__ b_hh,
                                            const float* __restrict__ W_hh,
                                            const float* __restrict__ fc_W,
                                            uint16_t* __restrict__ fcwb,
                                            uint16_t* __restrict__ XgT,
                                            uint16_t* __restrict__ hs,
                                            uint32_t* __restrict__ flags) {
    __shared__ uint16_t smem[64 * 520];   // LSTM: Wl (66560B) | worker: Al+Bl (46080B)
    const int bid  = blockIdx.x;
    const int tid  = threadIdx.x;
    const int w    = tid >> 6;
    const int lane = tid & 63;
    const int l15  = lane & 15;
    const int lhi  = lane >> 4;

    if (bid >= 32) {
        // ===================== workers: k1 tiles, then fc_W convert =====================
        uint16_t* Al = smem;              // [64*72]
        uint16_t* Bl = smem + 64 * 72;    // [256*72]
        for (int id = bid - 32; id < 408; id += 224) {
            const int t  = id >> 3;
            const int n0 = (id & 7) * 256;
            f32x4 acc[4][4];
            #pragma unroll
            for (int mi = 0; mi < 4; ++mi)
                #pragma unroll
                for (int nf = 0; nf < 4; ++nf) acc[mi][nf] = (f32x4){0.f, 0.f, 0.f, 0.f};
            for (int k0 = 0; k0 < H_; k0 += 64) {
                #pragma unroll
                for (int r = 0; r < 2; ++r) {       // A: 64x64 emb gather + convert
                    int idx = r * 256 + tid, row = idx >> 3, seg = idx & 7;
                    int tok = (t == 0) ? 1 : labels[row * 50 + (t - 1)];
                    const float* s = emb + (size_t)tok * H_ + k0 + seg * 8;
                    float4 f0 = *(const float4*)s;
                    float4 f1 = *(const float4*)(s + 4);
                    union { uint16_t h[8]; uint4 u; } p;
                    p.h[0]=f2bf(f0.x); p.h[1]=f2bf(f0.y); p.h[2]=f2bf(f0.z); p.h[3]=f2bf(f0.w);
                    p.h[4]=f2bf(f1.x); p.h[5]=f2bf(f1.y); p.h[6]=f2bf(f1.z); p.h[7]=f2bf(f1.w);
                    *(uint4*)(Al + row * 72 + seg * 8) = p.u;
                }
                #pragma unroll
                for (int r = 0; r < 8; ++r) {       // B: 256x64 W_ih convert
                    int idx = r * 256 + tid, row = idx >> 3, seg = idx & 7;
                    const float* s = W_ih + (size_t)(n0 + row) * H_ + k0 + seg * 8;
                    float4 f0 = *(const float4*)s;
                    float4 f1 = *(const float4*)(s + 4);
                    union { uint16_t h[8]; uint4 u; } p;
                    p.h[0]=f2bf(f0.x); p.h[1]=f2bf(f0.y); p.h[2]=f2bf(f0.z); p.h[3]=f2bf(f0.w);
                    p.h[4]=f2bf(f1.x); p.h[5]=f2bf(f1.y); p.h[6]=f2bf(f1.z); p.h[7]=f2bf(f1.w);
                    *(uint4*)(Bl + row * 72 + seg * 8) = p.u;
                }
                __syncthreads();
                #pragma unroll
                for (int ks = 0; ks < 2; ++ks) {
                    bf16x8 a[4];
                    #pragma unroll
                    for (int mi = 0; mi < 4; ++mi)
                        a[mi] = *(const bf16x8*)(Al + (mi * 16 + l15) * 72 + ks * 32 + lhi * 8);
                    #pragma unroll
                    for (int nf = 0; nf < 4; ++nf) {
                        bf16x8 b = *(const bf16x8*)(Bl + (w * 64 + nf * 16 + l15) * 72 + ks * 32 + lhi * 8);
                        #pragma unroll
                        for (int mi = 0; mi < 4; ++mi)
                            acc[mi][nf] = __builtin_amdgcn_mfma_f32_16x16x32_bf16(a[mi], b, acc[mi][nf], 0, 0, 0);
                    }
                }
                __syncthreads();
            }
            float bias[4];
            #pragma unroll
            for (int nf = 0; nf < 4; ++nf) {
                int col = n0 + w * 64 + nf * 16 + l15;
                bias[nf] = b_ih[col] + b_hh[col];
            }
            #pragma unroll
            for (int mi = 0; mi < 4; ++mi)
                #pragma unroll
                for (int nf = 0; nf < 4; ++nf) {
                    const int col = n0 + w * 64 + nf * 16 + l15;
                    const int g = col >> 9, u = col & 511;
                    const int b = mi * 16 + lhi * 4;
                    union { uint16_t h[4]; ull q; } pk;
                    #pragma unroll
                    for (int q = 0; q < 4; ++q) pk.h[q] = f2bf(acc[mi][nf][q] + bias[nf]);
                    stq(XgT + ((size_t)(t * 512 + u) * 4 + g) * 64 + b, pk.q);
                }
            asm volatile("s_waitcnt vmcnt(0)" ::: "memory");   // tile data at LLC
            __syncthreads();                                    // whole block drained
            if (tid == 0) stflag(flags + NHF + t * 8 + (n0 >> 8), 1u);
        }
        if (DOFC) {   // fc_W -> bf16 (coalesced grid-stride over 224 blocks)
            const int n8 = (V_ * H_) / 8;
            for (int i = (bid - 32) * 256 + tid; i < n8; i += 224 * 256) {
                const float4* s = (const float4*)fc_W + (size_t)i * 2;
                float4 f0 = s[0], f1 = s[1];
                union { uint16_t h[8]; uint4 u; } p;
                p.h[0]=f2bf(f0.x); p.h[1]=f2bf(f0.y); p.h[2]=f2bf(f0.z); p.h[3]=f2bf(f0.w);
                p.h[4]=f2bf(f1.x); p.h[5]=f2bf(f1.y); p.h[6]=f2bf(f1.z); p.h[7]=f2bf(f1.w);
                ((uint4*)fcwb)[i] = p.u;
            }
        }
        return;
    }

    // ===================== LSTM convoy (blocks 0..31, round-6 core) =====================
    uint16_t* Wl = smem;
    const int u0   = bid * 16;
    const int arow = w * 16 + l15;
    {   // W_hh slice -> bf16 LDS. LDS row c = g*16+uu <-> W row g*512+u0+uu
        const int c = tid >> 2;
        const int q = tid & 3;
        const int j = (c >> 4) * 512 + u0 + (c & 15);
        const float* src = W_hh + (size_t)j * H_ + q * 128;
        uint16_t* dst = Wl + c * 520 + q * 128;
        #pragma unroll
        for (int i = 0; i < 128; i += 8) {
            float4 f0 = *(const float4*)(src + i);
            float4 f1 = *(const float4*)(src + i + 4);
            union { uint16_t h[8]; uint4 u; } p;
            p.h[0]=f2bf(f0.x); p.h[1]=f2bf(f0.y); p.h[2]=f2bf(f0.z); p.h[3]=f2bf(f0.w);
            p.h[4]=f2bf(f1.x); p.h[5]=f2bf(f1.y); p.h[6]=f2bf(f1.z); p.h[7]=f2bf(f1.w);
            *(uint4*)(dst + i) = p.u;
        }
    }
    float cst[4];
    #pragma unroll
    for (int q = 0; q < 4; ++q)
        cst[q] = x[(size_t)(w * 16 + lhi * 4 + q) * H_ + u0 + l15];
    __syncthreads();                    // Wl ready (read-only afterwards)

    for (int t = 0; t < T_; ++t) {
        // ---- combined poll: h-flags(t-1) + Xg-tile-flags(t) in one loop ----
        const uint32_t* fp = flags;     // dummy init
        bool dopoll = false;
        if (t > 0 && lane < 32)      { fp = flags + (size_t)(t - 1) * 128 + lane * 4 + w; dopoll = true; }
        else if (lane >= 32 && lane < 40) { fp = flags + NHF + t * 8 + (lane - 32); dopoll = true; }
        else if (t == 0 && lane < 8) { fp = flags + NHF + (lane); dopoll = true; }  // t=0: xg only
        for (;;) {
            uint32_t fv = 1;
            if (dopoll) fv = ldflag(fp);
            if (!__any((int)(fv == 0))) break;
            __builtin_amdgcn_s_sleep(1);
        }
        __builtin_amdgcn_sched_barrier(0);

        u32x4 ha[16];
        ull xgp[4];
        if (t == 0) {
            const float* xb = x + (size_t)arow * H_ + lhi * 8;
            #pragma unroll
            for (int ks = 0; ks < 16; ++ks) {
                float4 f0 = *(const float4*)(xb + ks * 32);
                float4 f1 = *(const float4*)(xb + ks * 32 + 4);
                union { uint16_t h[8]; u32x4 u; } p;
                p.h[0]=f2bf(f0.x); p.h[1]=f2bf(f0.y); p.h[2]=f2bf(f0.z); p.h[3]=f2bf(f0.w);
                p.h[4]=f2bf(f1.x); p.h[5]=f2bf(f1.y); p.h[6]=f2bf(f1.z); p.h[7]=f2bf(f1.w);
                ha[ks] = p.u;
            }
        } else {
            const uint16_t* hb = hs + ((size_t)(t - 1) * 64 + arow) * H_ + lhi * 8;
            #pragma unroll
            for (int ks = 0; ks < 16; ++ks)
                ldsc(ha[ks], (const uint32_t*)(hb + ks * 32));
        }
        #pragma unroll
        for (int g = 0; g < 4; ++g)     // gate biases (LLC; consumed post-MFMA)
            ldq2(xgp[g], XgT + ((size_t)(t * 512 + u0 + l15) * 4 + g) * 64 + w * 16 + lhi * 4);

        f32x4 acc[4];
        #pragma unroll
        for (int nf = 0; nf < 4; ++nf) acc[nf] = (f32x4){0.f, 0.f, 0.f, 0.f};
        if (t != 0) { asm volatile("s_waitcnt vmcnt(12)" ::: "memory");   // ha[0..7] ready
                      __builtin_amdgcn_sched_barrier(0); }
        #pragma unroll
        for (int ks = 0; ks < 8; ++ks) {
            union { u32x4 u; bf16x8 v; } au; au.u = ha[ks];
            #pragma unroll
            for (int nf = 0; nf < 4; ++nf) {
                bf16x8 b = *(const bf16x8*)(Wl + (nf * 16 + l15) * 520 + ks * 32 + lhi * 8);
                acc[nf] = __builtin_amdgcn_mfma_f32_16x16x32_bf16(au.v, b, acc[nf], 0, 0, 0);
            }
        }
        asm volatile("s_waitcnt vmcnt(0)" ::: "memory");      // ha[8..15] + xgp ready
        __builtin_amdgcn_sched_barrier(0);
        #pragma unroll
        for (int ks = 8; ks < 16; ++ks) {
            union { u32x4 u; bf16x8 v; } au; au.u = ha[ks];
            #pragma unroll
            for (int nf = 0; nf < 4; ++nf) {
                bf16x8 b = *(const bf16x8*)(Wl + (nf * 16 + l15) * 520 + ks * 32 + lhi * 8);
                acc[nf] = __builtin_amdgcn_mfma_f32_16x16x32_bf16(au.v, b, acc[nf], 0, 0, 0);
            }
        }
        #pragma unroll
        for (int q = 0; q < 4; ++q) {
            const int b = w * 16 + lhi * 4 + q;
            float gi = acc[0][q] + bf2f((uint32_t)((xgp[0] >> (16 * q)) & 0xFFFF));
            float gf = acc[1][q] + bf2f((uint32_t)((xgp[1] >> (16 * q)) & 0xFFFF));
            float gg = acc[2][q] + bf2f((uint32_t)((xgp[2] >> (16 * q)) & 0xFFFF));
            float go = acc[3][q] + bf2f((uint32_t)((xgp[3] >> (16 * q)) & 0xFFFF));
            float si = 1.f / (1.f + __expf(-gi));
            float sf = 1.f / (1.f + __expf(-gf));
            float tg = tanhf(gg);
            float so = 1.f / (1.f + __expf(-go));
            float cc = sf * cst[q] + si * tg;
            cst[q] = cc;
            stsh(hs + (size_t)(t * 64 + b) * H_ + u0 + l15, (uint32_t)f2bf(so * tanhf(cc)));
        }
        asm volatile("s_waitcnt vmcnt(0)" ::: "memory");   // data at LLC
        if (lane == 0) stflag(flags + (size_t)t * 128 + bid * 4 + w, (uint32_t)(t + 1));
    }
}

// ---------------------------------------------------------------- K3: FC + lse (bf16 MFMA)
// m97-style: tile 128x256, BK=64, 8 waves. global_load_lds width 16,
// XOR-swizzled source+read (T2): conflict-free. 1D grid, bijective XCD swizzle.
template<int CVT>
__global__ __launch_bounds__(512, 4) void k3_mfma(const uint16_t* __restrict__ hsb,
                                                  const void* __restrict__ fcw,
                                                  const float* __restrict__ fc_b,
                                                  const int* __restrict__ labels,
                                                  float* __restrict__ sumexp,
                                                  float* __restrict__ tgtlog) {
    __shared__ uint16_t Al[128 * 64];   // 16 KB
    __shared__ uint16_t Bl[256 * 64];   // 32 KB
    const int flat = blockIdx.x;        // 3250 = 8*406+2: xcd 0,1 get 407
    const int xcd  = flat & 7;
    const int slot = flat >> 3;
    const int work = (xcd < 2 ? xcd * 407 : 814 + (xcd - 2) * 406) + slot;
    const int m0   = (work % 26) * 128;
    const int v0   = (work / 26) * 256;
    const int tid  = threadIdx.x;
    const int w    = tid >> 6;
    const int lane = tid & 63;
    const int l15  = lane & 15;
    const int lhi  = lane >> 4;
    const int wm   = w >> 2;
    const int wn   = w & 3;

    f32x4 acc[4][4];
    #pragma unroll
    for (int mi = 0; mi < 4; ++mi)
        #pragma unroll
        for (int nf = 0; nf < 4; ++nf) acc[mi][nf] = (f32x4){0.f, 0.f, 0.f, 0.f};

    const int lrow = lane >> 3;                 // 0..7 within 8-row group
    const int segp = (lane & 7) ^ lrow;         // pre-swizzled source seg

    for (int k0 = 0; k0 < H_; k0 += 64) {
        #pragma unroll
        for (int r = 0; r < 2; ++r) {           // A: 128x64
            const int g = w * 2 + r, row0 = g * 8;
            int grow = m0 + row0 + lrow; if (grow >= R_) grow = R_ - 1;
            gl_lds16(hsb + (size_t)grow * H_ + k0 + segp * 8, Al + row0 * 64);
        }
        if (CVT == 0) {
            #pragma unroll
            for (int r = 0; r < 4; ++r) {       // B: 256x64
                const int g = w * 4 + r, row0 = g * 8;
                gl_lds16((const uint16_t*)fcw + (size_t)(v0 + row0 + lrow) * H_ + k0 + segp * 8,
                         Bl + row0 * 64);
            }
        } else {
            #pragma unroll
            for (int r = 0; r < 4; ++r) {       // reg-stage + convert, swizzled write
                int idx = r * 512 + tid, row = idx >> 3, seg = idx & 7;
                const float* s = (const float*)fcw + (size_t)(v0 + row) * H_ + k0 + seg * 8;
                float4 f0 = *(const float4*)s;
                float4 f1 = *(const float4*)(s + 4);
                union { uint16_t h[8]; uint4 u; } p;
                p.h[0]=f2bf(f0.x); p.h[1]=f2bf(f0.y); p.h[2]=f2bf(f0.z); p.h[3]=f2bf(f0.w);
                p.h[4]=f2bf(f1.x); p.h[5]=f2bf(f1.y); p.h[6]=f2bf(f1.z); p.h[7]=f2bf(f1.w);
                *(uint4*)(Bl + row * 64 + (seg ^ (row & 7)) * 8) = p.u;
            }
        }
        __syncthreads();
        #pragma unroll
        for (int ks = 0; ks < 2; ++ks) {
            bf16x8 a[4];
            #pragma unroll
            for (int mi = 0; mi < 4; ++mi) {
                const int ar = wm * 64 + mi * 16 + l15;
                a[mi] = *(const bf16x8*)((const char*)Al + ar * 128 +
                        ((ks * 64 + lhi * 16) ^ ((ar & 7) << 4)));
            }
            #pragma unroll
            for (int nf = 0; nf < 4; ++nf) {
                const int br = wn * 64 + nf * 16 + l15;
                bf16x8 b = *(const bf16x8*)((const char*)Bl + br * 128 +
                           ((ks * 64 + lhi * 16) ^ ((br & 7) << 4)));
                #pragma unroll
                for (int mi = 0; mi < 4; ++mi)
                    acc[mi][nf] = __builtin_amdgcn_mfma_f32_16x16x32_bf16(a[mi], b, acc[mi][nf], 0, 0, 0);
            }
        }
        __syncthreads();
    }
    float bias[4];
    #pragma unroll
    for (int nf = 0; nf < 4; ++nf) bias[nf] = fc_b[v0 + wn * 64 + nf * 16 + l15];
    #pragma unroll
    for (int mi = 0; mi < 4; ++mi) {
        #pragma unroll
        for (int q = 0; q < 4; ++q) {
            const int r = m0 + wm * 64 + mi * 16 + lhi * 4 + q;
            if (r >= R_) continue;
            const int t = r >> 6, b = r & 63;
            const int tgt = (t < 50) ? labels[b * 50 + t] : 2;
            float lsum = 0.f;
            #pragma unroll
            for (int nf = 0; nf < 4; ++nf) {
                const int v = v0 + wn * 64 + nf * 16 + l15;
                float lg = acc[mi][nf][q] + bias[nf];
                lsum += __expf(lg);
                if (v == tgt) tgtlog[r] = lg;
            }
            lsum += __shfl_xor(lsum, 1, 16);
            lsum += __shfl_xor(lsum, 2, 16);
            lsum += __shfl_xor(lsum, 4, 16);
            lsum += __shfl_xor(lsum, 8, 16);
            if (l15 == 0) atomicAdd(&sumexp[r], lsum);
        }
    }
}

// ---------------------------------------------------------------- K4: loss
__global__ __launch_bounds__(256) void k4_loss(const float* __restrict__ sumexp,
                                               const float* __restrict__ tgtlog,
                                               float* __restrict__ out) {
    __shared__ float red[256];
    float s = 0.f;
    for (int r = threadIdx.x; r < R_; r += 256) s += logf(sumexp[r]) - tgtlog[r];
    red[threadIdx.x] = s;
    __syncthreads();
    for (int st = 128; st > 0; st >>= 1) {
        if (threadIdx.x < st) red[threadIdx.x] += red[threadIdx.x + st];
        __syncthreads();
    }
    if (threadIdx.x == 0) out[0] = red[0] / 64.0f;
}

// ----------------------------------------------------------------
extern "C" void kernel_launch(void* const* d_in, const int* in_sizes, int n_in,
                              void* d_out, int out_size, void* d_ws, size_t ws_size,
                              hipStream_t stream) {
    const float* x      = (const float*)d_in[0];
    const int*   labels = (const int*)d_in[1];
    const float* emb    = (const float*)d_in[2];
    const float* W_ih   = (const float*)d_in[3];
    const float* W_hh   = (const float*)d_in[4];
    const float* b_ih   = (const float*)d_in[5];
    const float* b_hh   = (const float*)d_in[6];
    const float* fc_W   = (const float*)d_in[7];
    const float* fc_b   = (const float*)d_in[8];
    float* out = (float*)d_out;

    char* p = (char*)d_ws;
    uint16_t* XgT    = (uint16_t*)p;  p += (size_t)T_ * 512 * 4 * 64 * 2;  // 13.4 MB
    uint16_t* hsb    = (uint16_t*)p;  p += (size_t)R_ * H_ * 2;            // 3.3 MB
    float*    sumexp = (float*)p;     p += (size_t)R_ * 4;
    float*    tgtl   = (float*)p;     p += (size_t)R_ * 4;
    uint32_t* flags  = (uint32_t*)p;  p += (size_t)(NHF + 512) * 4;        // 28 KB
    uint16_t* fcwb   = (uint16_t*)p;  p += (size_t)V_ * H_ * 2;            // 32.8 MB
    const bool pre = ((size_t)(p - (char*)d_ws) <= ws_size);

    k0_init<<<32, 256, 0, stream>>>(sumexp, flags);
    if (pre) {
        k12p<1><<<256, 256, 0, stream>>>(x, labels, emb, W_ih, b_ih, b_hh, W_hh,
                                         fc_W, fcwb, XgT, hsb, flags);
        k3_mfma<0><<<3250, 512, 0, stream>>>(hsb, fcwb, fc_b, labels, sumexp, tgtl);
    } else {
        k12p<0><<<256, 256, 0, stream>>>(x, labels, emb, W_ih, b_ih, b_hh, W_hh,
                                         fc_W, fcwb, XgT, hsb, flags);
        k3_mfma<1><<<3250, 512, 0, stream>>>(hsb, fc_W, fc_b, labels, sumexp, tgtl);
    }
    k4_loss<<<1, 256, 0, stream>>>(sumexp, tgtl, out);
}